// Round 1
// baseline (620.602 us; speedup 1.0000x reference)
//
#include <hip/hip_runtime.h>
#include <hip/hip_bf16.h>
#include <stddef.h>

// Problem constants (match reference setup_inputs)
#define N_NODES 100000
#define N_EDGES 20000
#define NNZ     1600000
#define DIM     128

typedef short bf16x8 __attribute__((ext_vector_type(8)));
typedef float f32x4  __attribute__((ext_vector_type(4)));

__device__ __forceinline__ short f2bf(float f) {
  union { float f; unsigned u; } c; c.f = f;
  unsigned r = c.u + 0x7FFFu + ((c.u >> 16) & 1u);   // round-to-nearest-even
  return (short)(r >> 16);
}

// ---------------- W fp32 -> bf16 ----------------
__global__ void convw_kernel(const float* __restrict__ W, short* __restrict__ Wb) {
  int i = blockIdx.x * 256 + threadIdx.x;
  if (i < DIM * DIM) Wb[i] = f2bf(W[i]);
}

// ---------------- GEMM: h = x @ W^T + b  (bf16 MFMA, fp32 accum) ----------------
// One wave computes 16 rows x 128 cols. mfma_f32_16x16x32_bf16, K=128 -> 4 mfma per o-tile.
__global__ __launch_bounds__(256) void gemm_kernel(
    const float* __restrict__ x, const short* __restrict__ Wb,
    const float* __restrict__ bias, float* __restrict__ h) {
  const int wid = threadIdx.x >> 6;
  const int l   = threadIdx.x & 63;
  const int n0  = (blockIdx.x * 4 + wid) * 16;
  if (n0 >= N_NODES) return;
  const int r  = l & 15;   // A-row within tile (also B-col within o-tile)
  const int kg = l >> 4;   // k-group (8 consecutive k per group)

  // A fragments: 4 k-chunks of this wave's 16 x rows (convert fp32->bf16 inline)
  bf16x8 a[4];
  {
    const float* xr = x + (size_t)(n0 + r) * DIM + kg * 8;
    #pragma unroll
    for (int kc = 0; kc < 4; ++kc) {
      const float4* p = reinterpret_cast<const float4*>(xr + kc * 32);
      float4 f0 = p[0], f1 = p[1];
      bf16x8 av;
      av[0]=f2bf(f0.x); av[1]=f2bf(f0.y); av[2]=f2bf(f0.z); av[3]=f2bf(f0.w);
      av[4]=f2bf(f1.x); av[5]=f2bf(f1.y); av[6]=f2bf(f1.z); av[7]=f2bf(f1.w);
      a[kc] = av;
    }
  }

  f32x4 acc[8];
  #pragma unroll
  for (int ot = 0; ot < 8; ++ot) acc[ot] = (f32x4){0.f, 0.f, 0.f, 0.f};

  #pragma unroll
  for (int ot = 0; ot < 8; ++ot) {
    const short* wr = Wb + (size_t)(ot * 16 + r) * DIM + kg * 8;
    #pragma unroll
    for (int kc = 0; kc < 4; ++kc) {
      bf16x8 bfrag = *reinterpret_cast<const bf16x8*>(wr + kc * 32);
      acc[ot] = __builtin_amdgcn_mfma_f32_16x16x32_bf16(a[kc], bfrag, acc[ot], 0, 0, 0);
    }
  }

  // C/D layout: col = lane&15, row = (lane>>4)*4 + reg   [m89-verified]
  #pragma unroll
  for (int ot = 0; ot < 8; ++ot) {
    const int o  = ot * 16 + r;
    const float bv = bias[o];
    #pragma unroll
    for (int j = 0; j < 4; ++j) {
      const int row = kg * 4 + j;
      h[(size_t)(n0 + row) * DIM + o] = acc[ot][j] + bv;
    }
  }
}

// ---------------- degree histogram ----------------
__global__ void hist_kernel(const int* __restrict__ ni, const int* __restrict__ ei,
                            int* __restrict__ dn, int* __restrict__ de) {
  int i = blockIdx.x * 256 + threadIdx.x;
  if (i < NNZ) {
    atomicAdd(&dn[ni[i]], 1);
    atomicAdd(&de[ei[i]], 1);
  }
}

// ---------------- hierarchical exclusive scan ----------------
// Per-block exclusive scan + block totals (Hillis-Steele in LDS).
__global__ void scan_block_kernel(const int* __restrict__ in, int* __restrict__ out,
                                  int* __restrict__ bsums, int n) {
  __shared__ int lds[512];
  const int tx = threadIdx.x;
  const int i  = blockIdx.x * blockDim.x + tx;
  int v = (i < n) ? in[i] : 0;
  int x = v;
  lds[tx] = x;
  __syncthreads();
  for (int off = 1; off < (int)blockDim.x; off <<= 1) {
    int t = (tx >= off) ? lds[tx - off] : 0;
    __syncthreads();
    x += t;
    lds[tx] = x;
    __syncthreads();
  }
  if (i < n) out[i] = x - v;                 // exclusive
  if (bsums && tx == (int)blockDim.x - 1) bsums[blockIdx.x] = x;  // total
}

__global__ void scan_add_kernel(int* __restrict__ out, const int* __restrict__ bsums, int n) {
  int i = blockIdx.x * blockDim.x + threadIdx.x;
  if (i < n) out[i] += bsums[blockIdx.x];
}

// ---------------- CSR scatter (atomic cursors) ----------------
__global__ void scatter_kernel(const int* __restrict__ ni, const int* __restrict__ ei,
                               const int* __restrict__ off_n, const int* __restrict__ off_e,
                               int* __restrict__ cur_n, int* __restrict__ cur_e,
                               int* __restrict__ csr_e2n, int* __restrict__ csr_n2e) {
  int i = blockIdx.x * 256 + threadIdx.x;
  if (i < NNZ) {
    int n = ni[i], e = ei[i];
    int pe = off_e[e] + atomicAdd(&cur_e[e], 1);
    csr_e2n[pe] = n;
    int pn = off_n[n] + atomicAdd(&cur_n[n], 1);
    csr_n2e[pn] = e;
  }
}

// ---------------- hop 1: m01[e,:] = sum_{n in edge e} h[n,:] ----------------
__global__ __launch_bounds__(128) void hop1_kernel(
    const float* __restrict__ h, const int* __restrict__ off_e,
    const int* __restrict__ deg_e, const int* __restrict__ csr_e2n,
    float* __restrict__ m01) {
  const int e = blockIdx.x;
  const int d = threadIdx.x;
  const int s   = off_e[e];
  const int cnt = deg_e[e];
  float acc = 0.0f;
  int j = 0;
  for (; j + 4 <= cnt; j += 4) {
    const int n0 = csr_e2n[s + j + 0];
    const int n1 = csr_e2n[s + j + 1];
    const int n2 = csr_e2n[s + j + 2];
    const int n3 = csr_e2n[s + j + 3];
    const float v0 = h[(size_t)n0 * DIM + d];
    const float v1 = h[(size_t)n1 * DIM + d];
    const float v2 = h[(size_t)n2 * DIM + d];
    const float v3 = h[(size_t)n3 * DIM + d];
    acc += v0 + v1 + v2 + v3;
  }
  for (; j < cnt; ++j) acc += h[(size_t)csr_e2n[s + j] * DIM + d];
  m01[(size_t)e * DIM + d] = acc;
}

// ---------------- hop 2 + finalize: out[n,:] = h[n,:] + mean_{e ni n} m01[e,:] ----------------
__global__ __launch_bounds__(128) void hop2_kernel(
    const float* __restrict__ h, const int* __restrict__ off_n,
    const int* __restrict__ deg_n, const int* __restrict__ csr_n2e,
    const float* __restrict__ m01, float* __restrict__ out) {
  const int n = blockIdx.x;
  const int d = threadIdx.x;
  const int s   = off_n[n];
  const int cnt = deg_n[n];
  float acc = 0.0f;
  int j = 0;
  for (; j + 4 <= cnt; j += 4) {
    const int e0 = csr_n2e[s + j + 0];
    const int e1 = csr_n2e[s + j + 1];
    const int e2 = csr_n2e[s + j + 2];
    const int e3 = csr_n2e[s + j + 3];
    const float v0 = m01[(size_t)e0 * DIM + d];
    const float v1 = m01[(size_t)e1 * DIM + d];
    const float v2 = m01[(size_t)e2 * DIM + d];
    const float v3 = m01[(size_t)e3 * DIM + d];
    acc += v0 + v1 + v2 + v3;
  }
  for (; j < cnt; ++j) acc += m01[(size_t)csr_n2e[s + j] * DIM + d];
  const float inv = 1.0f / (float)(cnt > 0 ? cnt : 1);
  out[(size_t)n * DIM + d] = h[(size_t)n * DIM + d] + acc * inv;
}

extern "C" void kernel_launch(void* const* d_in, const int* in_sizes, int n_in,
                              void* d_out, int out_size, void* d_ws, size_t ws_size,
                              hipStream_t stream) {
  const float* x    = (const float*)d_in[0];
  const float* W    = (const float*)d_in[1];
  const float* bias = (const float*)d_in[2];
  const int*   ni   = (const int*)d_in[3];
  const int*   ei   = (const int*)d_in[4];
  float* out = (float*)d_out;

  // ---- workspace carve ----
  char* ws = (char*)d_ws;
  size_t o = 0;
  auto carve = [&](size_t bytes) -> char* {
    char* p = ws + o;
    o = (o + bytes + 255) & ~(size_t)255;
    return p;
  };
  float* h        = (float*)carve((size_t)N_NODES * DIM * 4);   // 51.2 MB
  float* m01      = (float*)carve((size_t)N_EDGES * DIM * 4);   // 10.24 MB
  int*   csr_e2n  = (int*)  carve((size_t)NNZ * 4);             // 6.4 MB
  int*   csr_n2e  = (int*)  carve((size_t)NNZ * 4);             // 6.4 MB
  short* Wb       = (short*)carve((size_t)DIM * DIM * 2);       // 32 KB
  size_t zero_beg = o;
  int*   deg_n    = (int*)carve((size_t)N_NODES * 4);
  int*   deg_e    = (int*)carve((size_t)N_EDGES * 4);
  int*   cur_n    = (int*)carve((size_t)N_NODES * 4);
  int*   cur_e    = (int*)carve((size_t)N_EDGES * 4);
  size_t zero_end = o;
  int*   off_n    = (int*)carve((size_t)N_NODES * 4);
  int*   off_e    = (int*)carve((size_t)N_EDGES * 4);
  int*   bsums    = (int*)carve(512 * 4);
  (void)ws_size; (void)in_sizes; (void)n_in; (void)out_size;

  // ---- zero degree/cursor arrays (poisoned workspace; must re-zero every call) ----
  hipMemsetAsync(ws + zero_beg, 0, zero_end - zero_beg, stream);

  // ---- W -> bf16 ----
  convw_kernel<<<(DIM * DIM + 255) / 256, 256, 0, stream>>>(W, Wb);

  // ---- GEMM h = x W^T + b ----
  gemm_kernel<<<(N_NODES / 16 + 3) / 4, 256, 0, stream>>>(x, Wb, bias, h);

  // ---- degree histogram ----
  hist_kernel<<<NNZ / 256, 256, 0, stream>>>(ni, ei, deg_n, deg_e);

  // ---- exclusive scans: deg -> offsets ----
  {
    int nbl_e = (N_EDGES + 255) / 256;   // 79
    scan_block_kernel<<<nbl_e, 256, 0, stream>>>(deg_e, off_e, bsums, N_EDGES);
    scan_block_kernel<<<1, 512, 0, stream>>>(bsums, bsums, nullptr, nbl_e);
    scan_add_kernel<<<nbl_e, 256, 0, stream>>>(off_e, bsums, N_EDGES);

    int nbl_n = (N_NODES + 255) / 256;   // 391
    scan_block_kernel<<<nbl_n, 256, 0, stream>>>(deg_n, off_n, bsums, N_NODES);
    scan_block_kernel<<<1, 512, 0, stream>>>(bsums, bsums, nullptr, nbl_n);
    scan_add_kernel<<<nbl_n, 256, 0, stream>>>(off_n, bsums, N_NODES);
  }

  // ---- CSR scatter ----
  scatter_kernel<<<NNZ / 256, 256, 0, stream>>>(ni, ei, off_n, off_e,
                                                cur_n, cur_e, csr_e2n, csr_n2e);

  // ---- hops ----
  hop1_kernel<<<N_EDGES, 128, 0, stream>>>(h, off_e, deg_e, csr_e2n, m01);
  hop2_kernel<<<N_NODES, 128, 0, stream>>>(h, off_n, deg_n, csr_n2e, m01, out);
}

// Round 2
// 441.561 us; speedup vs baseline: 1.4055x; 1.4055x over previous
//
#include <hip/hip_runtime.h>
#include <hip/hip_bf16.h>
#include <stddef.h>

// Problem constants (match reference setup_inputs)
#define N_NODES 100000
#define N_EDGES 20000
#define NNZ     1600000
#define DIM     128

typedef short bf16x8 __attribute__((ext_vector_type(8)));
typedef float f32x4  __attribute__((ext_vector_type(4)));

__device__ __forceinline__ short f2bf(float f) {
  union { float f; unsigned u; } c; c.f = f;
  unsigned r = c.u + 0x7FFFu + ((c.u >> 16) & 1u);   // round-to-nearest-even
  return (short)(r >> 16);
}

// ---------------- W fp32 -> bf16 ----------------
__global__ void convw_kernel(const float* __restrict__ W, short* __restrict__ Wb) {
  int i = blockIdx.x * 256 + threadIdx.x;
  if (i < DIM * DIM) Wb[i] = f2bf(W[i]);
}

// ---------------- GEMM: h = x @ W^T + b  (bf16 MFMA, fp32 accum) ----------------
__global__ __launch_bounds__(256) void gemm_kernel(
    const float* __restrict__ x, const short* __restrict__ Wb,
    const float* __restrict__ bias, float* __restrict__ h) {
  const int wid = threadIdx.x >> 6;
  const int l   = threadIdx.x & 63;
  const int n0  = (blockIdx.x * 4 + wid) * 16;
  if (n0 >= N_NODES) return;
  const int r  = l & 15;   // A-row within tile (also B-col within o-tile)
  const int kg = l >> 4;   // k-group (8 consecutive k per group)

  bf16x8 a[4];
  {
    const float* xr = x + (size_t)(n0 + r) * DIM + kg * 8;
    #pragma unroll
    for (int kc = 0; kc < 4; ++kc) {
      const float4* p = reinterpret_cast<const float4*>(xr + kc * 32);
      float4 f0 = p[0], f1 = p[1];
      bf16x8 av;
      av[0]=f2bf(f0.x); av[1]=f2bf(f0.y); av[2]=f2bf(f0.z); av[3]=f2bf(f0.w);
      av[4]=f2bf(f1.x); av[5]=f2bf(f1.y); av[6]=f2bf(f1.z); av[7]=f2bf(f1.w);
      a[kc] = av;
    }
  }

  f32x4 acc[8];
  #pragma unroll
  for (int ot = 0; ot < 8; ++ot) acc[ot] = (f32x4){0.f, 0.f, 0.f, 0.f};

  #pragma unroll
  for (int ot = 0; ot < 8; ++ot) {
    const short* wr = Wb + (size_t)(ot * 16 + r) * DIM + kg * 8;
    #pragma unroll
    for (int kc = 0; kc < 4; ++kc) {
      bf16x8 bfrag = *reinterpret_cast<const bf16x8*>(wr + kc * 32);
      acc[ot] = __builtin_amdgcn_mfma_f32_16x16x32_bf16(a[kc], bfrag, acc[ot], 0, 0, 0);
    }
  }

  // C/D layout: col = lane&15, row = (lane>>4)*4 + reg   [m89-verified]
  #pragma unroll
  for (int ot = 0; ot < 8; ++ot) {
    const int o  = ot * 16 + r;
    const float bv = bias[o];
    #pragma unroll
    for (int j = 0; j < 4; ++j) {
      const int row = kg * 4 + j;
      h[(size_t)(n0 + row) * DIM + o] = acc[ot][j] + bv;
    }
  }
}

// ---------------- degree histogram + per-element rank (atomic returns) ----------------
__global__ void hist_kernel(const int* __restrict__ ni, const int* __restrict__ ei,
                            int* __restrict__ dn, int* __restrict__ de,
                            unsigned* __restrict__ rank) {
  int i = blockIdx.x * 256 + threadIdx.x;
  if (i < NNZ) {
    unsigned rn = (unsigned)atomicAdd(&dn[ni[i]], 1);
    unsigned re = (unsigned)atomicAdd(&de[ei[i]], 1);
    rank[i] = re | (rn << 16);   // deg_e < 65536, deg_n < 65536 (Poisson(80)/(16))
  }
}

// ---------------- hierarchical exclusive scan ----------------
__global__ void scan_block_kernel(const int* __restrict__ in, int* __restrict__ out,
                                  int* __restrict__ bsums, int n) {
  __shared__ int lds[512];
  const int tx = threadIdx.x;
  const int i  = blockIdx.x * blockDim.x + tx;
  int v = (i < n) ? in[i] : 0;
  int x = v;
  lds[tx] = x;
  __syncthreads();
  for (int off = 1; off < (int)blockDim.x; off <<= 1) {
    int t = (tx >= off) ? lds[tx - off] : 0;
    __syncthreads();
    x += t;
    lds[tx] = x;
    __syncthreads();
  }
  if (i < n) out[i] = x - v;                 // exclusive
  if (bsums && tx == (int)blockDim.x - 1) bsums[blockIdx.x] = x;  // total
}

__global__ void scan_add_kernel(int* __restrict__ out, const int* __restrict__ bsums, int n) {
  int i = blockIdx.x * blockDim.x + threadIdx.x;
  if (i < n) out[i] += bsums[blockIdx.x];
}

// ---------------- CSR scatter: pure stores, no atomics ----------------
__global__ void scatter_kernel(const int* __restrict__ ni, const int* __restrict__ ei,
                               const int* __restrict__ off_n, const int* __restrict__ off_e,
                               const unsigned* __restrict__ rank,
                               int* __restrict__ csr_e2n, int* __restrict__ csr_n2e) {
  int i = blockIdx.x * 256 + threadIdx.x;
  if (i < NNZ) {
    int n = ni[i], e = ei[i];
    unsigned r = rank[i];
    csr_e2n[off_e[e] + (int)(r & 0xFFFFu)] = n;
    csr_n2e[off_n[n] + (int)(r >> 16)]     = e;
  }
}

// ---------------- hop 1: m01[e,:] = sum_{n in edge e} h[n,:] ----------------
// 128 threads = 4 groups x 32 lanes; each group handles one CSR entry at a
// time, each lane loads float4 (16B) -> a 32-lane group covers a 512B row.
__global__ __launch_bounds__(128) void hop1_kernel(
    const float* __restrict__ h, const int* __restrict__ off_e,
    const int* __restrict__ deg_e, const int* __restrict__ csr_e2n,
    float* __restrict__ m01) {
  const int e = blockIdx.x;
  const int g = threadIdx.x >> 5;   // 0..3
  const int l = threadIdx.x & 31;
  const int s   = off_e[e];
  const int cnt = deg_e[e];

  f32x4 a0 = (f32x4){0.f,0.f,0.f,0.f}, a1 = a0;
  int j = g;
  for (; j + 12 < cnt; j += 16) {   // 4 entries per group per iter (stride 4)
    const int n0 = csr_e2n[s + j + 0];
    const int n1 = csr_e2n[s + j + 4];
    const int n2 = csr_e2n[s + j + 8];
    const int n3 = csr_e2n[s + j + 12];
    f32x4 v0 = *reinterpret_cast<const f32x4*>(&h[(size_t)n0 * DIM + l * 4]);
    f32x4 v1 = *reinterpret_cast<const f32x4*>(&h[(size_t)n1 * DIM + l * 4]);
    f32x4 v2 = *reinterpret_cast<const f32x4*>(&h[(size_t)n2 * DIM + l * 4]);
    f32x4 v3 = *reinterpret_cast<const f32x4*>(&h[(size_t)n3 * DIM + l * 4]);
    a0 += v0 + v2;
    a1 += v1 + v3;
  }
  for (; j < cnt; j += 4) {
    const int n = csr_e2n[s + j];
    a0 += *reinterpret_cast<const f32x4*>(&h[(size_t)n * DIM + l * 4]);
  }

  __shared__ f32x4 red[128];
  red[threadIdx.x] = a0 + a1;
  __syncthreads();
  if (g == 0) {
    f32x4 r = red[l] + red[32 + l] + red[64 + l] + red[96 + l];
    *reinterpret_cast<f32x4*>(&m01[(size_t)e * DIM + l * 4]) = r;
  }
}

// ---------------- hop 2 + finalize: out[n,:] = h[n,:] + mean_{e ni n} m01[e,:] ----------------
__global__ __launch_bounds__(128) void hop2_kernel(
    const float* __restrict__ h, const int* __restrict__ off_n,
    const int* __restrict__ deg_n, const int* __restrict__ csr_n2e,
    const float* __restrict__ m01, float* __restrict__ out) {
  const int n = blockIdx.x;
  const int g = threadIdx.x >> 5;
  const int l = threadIdx.x & 31;
  const int s   = off_n[n];
  const int cnt = deg_n[n];

  f32x4 a0 = (f32x4){0.f,0.f,0.f,0.f}, a1 = a0;
  int j = g;
  for (; j + 12 < cnt; j += 16) {
    const int e0 = csr_n2e[s + j + 0];
    const int e1 = csr_n2e[s + j + 4];
    const int e2 = csr_n2e[s + j + 8];
    const int e3 = csr_n2e[s + j + 12];
    f32x4 v0 = *reinterpret_cast<const f32x4*>(&m01[(size_t)e0 * DIM + l * 4]);
    f32x4 v1 = *reinterpret_cast<const f32x4*>(&m01[(size_t)e1 * DIM + l * 4]);
    f32x4 v2 = *reinterpret_cast<const f32x4*>(&m01[(size_t)e2 * DIM + l * 4]);
    f32x4 v3 = *reinterpret_cast<const f32x4*>(&m01[(size_t)e3 * DIM + l * 4]);
    a0 += v0 + v2;
    a1 += v1 + v3;
  }
  for (; j < cnt; j += 4) {
    const int e = csr_n2e[s + j];
    a0 += *reinterpret_cast<const f32x4*>(&m01[(size_t)e * DIM + l * 4]);
  }

  __shared__ f32x4 red[128];
  red[threadIdx.x] = a0 + a1;
  __syncthreads();
  if (g == 0) {
    f32x4 r = red[l] + red[32 + l] + red[64 + l] + red[96 + l];
    f32x4 hv = *reinterpret_cast<const f32x4*>(&h[(size_t)n * DIM + l * 4]);
    const float inv = 1.0f / (float)(cnt > 0 ? cnt : 1);
    *reinterpret_cast<f32x4*>(&out[(size_t)n * DIM + l * 4]) = hv + r * inv;
  }
}

extern "C" void kernel_launch(void* const* d_in, const int* in_sizes, int n_in,
                              void* d_out, int out_size, void* d_ws, size_t ws_size,
                              hipStream_t stream) {
  const float* x    = (const float*)d_in[0];
  const float* W    = (const float*)d_in[1];
  const float* bias = (const float*)d_in[2];
  const int*   ni   = (const int*)d_in[3];
  const int*   ei   = (const int*)d_in[4];
  float* out = (float*)d_out;

  // ---- workspace carve ----
  char* ws = (char*)d_ws;
  size_t o = 0;
  auto carve = [&](size_t bytes) -> char* {
    char* p = ws + o;
    o = (o + bytes + 255) & ~(size_t)255;
    return p;
  };
  float*    h        = (float*)   carve((size_t)N_NODES * DIM * 4);   // 51.2 MB
  float*    m01      = (float*)   carve((size_t)N_EDGES * DIM * 4);   // 10.24 MB
  int*      csr_e2n  = (int*)     carve((size_t)NNZ * 4);             // 6.4 MB
  int*      csr_n2e  = (int*)     carve((size_t)NNZ * 4);             // 6.4 MB
  unsigned* rank     = (unsigned*)carve((size_t)NNZ * 4);             // 6.4 MB
  short*    Wb       = (short*)   carve((size_t)DIM * DIM * 2);       // 32 KB
  size_t zero_beg = o;
  int*      deg_n    = (int*)carve((size_t)N_NODES * 4);
  int*      deg_e    = (int*)carve((size_t)N_EDGES * 4);
  size_t zero_end = o;
  int*      off_n    = (int*)carve((size_t)N_NODES * 4);
  int*      off_e    = (int*)carve((size_t)N_EDGES * 4);
  int*      bsums    = (int*)carve(512 * 4);
  (void)ws_size; (void)in_sizes; (void)n_in; (void)out_size;

  // ---- zero degree arrays (workspace is poisoned; re-zero every call) ----
  hipMemsetAsync(ws + zero_beg, 0, zero_end - zero_beg, stream);

  // ---- W -> bf16 ----
  convw_kernel<<<(DIM * DIM + 255) / 256, 256, 0, stream>>>(W, Wb);

  // ---- GEMM h = x W^T + b ----
  gemm_kernel<<<(N_NODES / 16 + 3) / 4, 256, 0, stream>>>(x, Wb, bias, h);

  // ---- degree histogram + ranks ----
  hist_kernel<<<NNZ / 256, 256, 0, stream>>>(ni, ei, deg_n, deg_e, rank);

  // ---- exclusive scans: deg -> offsets ----
  {
    int nbl_e = (N_EDGES + 255) / 256;   // 79
    scan_block_kernel<<<nbl_e, 256, 0, stream>>>(deg_e, off_e, bsums, N_EDGES);
    scan_block_kernel<<<1, 512, 0, stream>>>(bsums, bsums, nullptr, nbl_e);
    scan_add_kernel<<<nbl_e, 256, 0, stream>>>(off_e, bsums, N_EDGES);

    int nbl_n = (N_NODES + 255) / 256;   // 391
    scan_block_kernel<<<nbl_n, 256, 0, stream>>>(deg_n, off_n, bsums, N_NODES);
    scan_block_kernel<<<1, 512, 0, stream>>>(bsums, bsums, nullptr, nbl_n);
    scan_add_kernel<<<nbl_n, 256, 0, stream>>>(off_n, bsums, N_NODES);
  }

  // ---- CSR scatter (pure stores) ----
  scatter_kernel<<<NNZ / 256, 256, 0, stream>>>(ni, ei, off_n, off_e, rank,
                                                csr_e2n, csr_n2e);

  // ---- hops ----
  hop1_kernel<<<N_EDGES, 128, 0, stream>>>(h, off_e, deg_e, csr_e2n, m01);
  hop2_kernel<<<N_NODES, 128, 0, stream>>>(h, off_n, deg_n, csr_n2e, m01, out);
}

// Round 3
// 433.504 us; speedup vs baseline: 1.4316x; 1.0186x over previous
//
#include <hip/hip_runtime.h>
#include <hip/hip_bf16.h>
#include <stddef.h>

// Problem constants (match reference setup_inputs)
#define N_NODES 100000
#define N_EDGES 20000
#define NNZ     1600000
#define DIM     128

// Counter padding strides (in int units) to break same-line atomic serialization
#define PAD_E 16   // deg_e: one counter per 64B line  (avg 80 hits/key)
#define PAD_N 8    // deg_n: two counters per 64B line (avg 16 hits/key)

typedef short bf16x8 __attribute__((ext_vector_type(8)));
typedef float f32x4  __attribute__((ext_vector_type(4)));

__device__ __forceinline__ short f2bf(float f) {
  union { float f; unsigned u; } c; c.f = f;
  unsigned r = c.u + 0x7FFFu + ((c.u >> 16) & 1u);   // round-to-nearest-even
  return (short)(r >> 16);
}

// ---------------- W fp32 -> bf16 ----------------
__global__ void convw_kernel(const float* __restrict__ W, short* __restrict__ Wb) {
  int i = blockIdx.x * 256 + threadIdx.x;
  if (i < DIM * DIM) Wb[i] = f2bf(W[i]);
}

// ---------------- GEMM: h = x @ W^T + b  (bf16 MFMA, fp32 accum) ----------------
__global__ __launch_bounds__(256) void gemm_kernel(
    const float* __restrict__ x, const short* __restrict__ Wb,
    const float* __restrict__ bias, float* __restrict__ h) {
  const int wid = threadIdx.x >> 6;
  const int l   = threadIdx.x & 63;
  const int n0  = (blockIdx.x * 4 + wid) * 16;
  if (n0 >= N_NODES) return;
  const int r  = l & 15;   // A-row within tile (also B-col within o-tile)
  const int kg = l >> 4;   // k-group (8 consecutive k per group)

  bf16x8 a[4];
  {
    const float* xr = x + (size_t)(n0 + r) * DIM + kg * 8;
    #pragma unroll
    for (int kc = 0; kc < 4; ++kc) {
      const float4* p = reinterpret_cast<const float4*>(xr + kc * 32);
      float4 f0 = p[0], f1 = p[1];
      bf16x8 av;
      av[0]=f2bf(f0.x); av[1]=f2bf(f0.y); av[2]=f2bf(f0.z); av[3]=f2bf(f0.w);
      av[4]=f2bf(f1.x); av[5]=f2bf(f1.y); av[6]=f2bf(f1.z); av[7]=f2bf(f1.w);
      a[kc] = av;
    }
  }

  f32x4 acc[8];
  #pragma unroll
  for (int ot = 0; ot < 8; ++ot) acc[ot] = (f32x4){0.f, 0.f, 0.f, 0.f};

  #pragma unroll
  for (int ot = 0; ot < 8; ++ot) {
    const short* wr = Wb + (size_t)(ot * 16 + r) * DIM + kg * 8;
    #pragma unroll
    for (int kc = 0; kc < 4; ++kc) {
      bf16x8 bfrag = *reinterpret_cast<const bf16x8*>(wr + kc * 32);
      acc[ot] = __builtin_amdgcn_mfma_f32_16x16x32_bf16(a[kc], bfrag, acc[ot], 0, 0, 0);
    }
  }

  // C/D layout: col = lane&15, row = (lane>>4)*4 + reg   [m89-verified]
  #pragma unroll
  for (int ot = 0; ot < 8; ++ot) {
    const int o  = ot * 16 + r;
    const float bv = bias[o];
    #pragma unroll
    for (int j = 0; j < 4; ++j) {
      const int row = kg * 4 + j;
      h[(size_t)(n0 + row) * DIM + o] = acc[ot][j] + bv;
    }
  }
}

// ---------------- degree histogram + per-element rank (padded counters, 2 nnz/thread) ----------------
__global__ void hist_kernel(const int* __restrict__ ni, const int* __restrict__ ei,
                            int* __restrict__ dn, int* __restrict__ de,
                            unsigned* __restrict__ rank) {
  const int i0 = blockIdx.x * 512 + threadIdx.x;
  const int i1 = i0 + 256;
  const int n0 = ni[i0], n1 = ni[i1];
  const int e0 = ei[i0], e1 = ei[i1];
  unsigned rn0 = (unsigned)atomicAdd(&dn[n0 * PAD_N], 1);
  unsigned re0 = (unsigned)atomicAdd(&de[e0 * PAD_E], 1);
  unsigned rn1 = (unsigned)atomicAdd(&dn[n1 * PAD_N], 1);
  unsigned re1 = (unsigned)atomicAdd(&de[e1 * PAD_E], 1);
  rank[i0] = re0 | (rn0 << 16);   // deg < 65536 always holds here
  rank[i1] = re1 | (rn1 << 16);
}

// ---------------- hierarchical exclusive scan (strided input) ----------------
__global__ void scan_block_kernel(const int* __restrict__ in, int stride,
                                  int* __restrict__ out,
                                  int* __restrict__ bsums, int n) {
  __shared__ int lds[512];
  const int tx = threadIdx.x;
  const int i  = blockIdx.x * blockDim.x + tx;
  int v = (i < n) ? in[(size_t)i * stride] : 0;
  int x = v;
  lds[tx] = x;
  __syncthreads();
  for (int off = 1; off < (int)blockDim.x; off <<= 1) {
    int t = (tx >= off) ? lds[tx - off] : 0;
    __syncthreads();
    x += t;
    lds[tx] = x;
    __syncthreads();
  }
  if (i < n) out[i] = x - v;                 // exclusive
  if (bsums && tx == (int)blockDim.x - 1) bsums[blockIdx.x] = x;  // total
}

__global__ void scan_add_kernel(int* __restrict__ out, const int* __restrict__ bsums, int n) {
  int i = blockIdx.x * blockDim.x + threadIdx.x;
  if (i < n) out[i] += bsums[blockIdx.x];
}

// ---------------- CSR scatter: pure stores, no atomics ----------------
__global__ void scatter_kernel(const int* __restrict__ ni, const int* __restrict__ ei,
                               const int* __restrict__ off_n, const int* __restrict__ off_e,
                               const unsigned* __restrict__ rank,
                               int* __restrict__ csr_e2n, int* __restrict__ csr_n2e) {
  int i = blockIdx.x * 256 + threadIdx.x;
  if (i < NNZ) {
    int n = ni[i], e = ei[i];
    unsigned r = rank[i];
    csr_e2n[off_e[e] + (int)(r & 0xFFFFu)] = n;
    csr_n2e[off_n[n] + (int)(r >> 16)]     = e;
  }
}

// ---------------- hop 1: m01[e,:] = sum_{n in edge e} h[n,:] ----------------
// 128 threads = 4 groups x 32 lanes; lane loads float4 -> group covers 512B row.
__global__ __launch_bounds__(128) void hop1_kernel(
    const float* __restrict__ h, const int* __restrict__ off_e,
    const int* __restrict__ csr_e2n, float* __restrict__ m01) {
  const int e = blockIdx.x;
  const int g = threadIdx.x >> 5;   // 0..3
  const int l = threadIdx.x & 31;
  const int s   = off_e[e];
  const int end = (e == N_EDGES - 1) ? NNZ : off_e[e + 1];
  const int cnt = end - s;

  f32x4 a0 = (f32x4){0.f,0.f,0.f,0.f}, a1 = a0;
  int j = g;
  for (; j + 12 < cnt; j += 16) {   // 4 entries per group per iter (stride 4)
    const int n0 = csr_e2n[s + j + 0];
    const int n1 = csr_e2n[s + j + 4];
    const int n2 = csr_e2n[s + j + 8];
    const int n3 = csr_e2n[s + j + 12];
    f32x4 v0 = *reinterpret_cast<const f32x4*>(&h[(size_t)n0 * DIM + l * 4]);
    f32x4 v1 = *reinterpret_cast<const f32x4*>(&h[(size_t)n1 * DIM + l * 4]);
    f32x4 v2 = *reinterpret_cast<const f32x4*>(&h[(size_t)n2 * DIM + l * 4]);
    f32x4 v3 = *reinterpret_cast<const f32x4*>(&h[(size_t)n3 * DIM + l * 4]);
    a0 += v0 + v2;
    a1 += v1 + v3;
  }
  for (; j < cnt; j += 4) {
    const int n = csr_e2n[s + j];
    a0 += *reinterpret_cast<const f32x4*>(&h[(size_t)n * DIM + l * 4]);
  }

  __shared__ f32x4 red[128];
  red[threadIdx.x] = a0 + a1;
  __syncthreads();
  if (g == 0) {
    f32x4 r = red[l] + red[32 + l] + red[64 + l] + red[96 + l];
    *reinterpret_cast<f32x4*>(&m01[(size_t)e * DIM + l * 4]) = r;
  }
}

// ---------------- hop 2 + finalize: out[n,:] = h[n,:] + mean_{e ni n} m01[e,:] ----------------
__global__ __launch_bounds__(128) void hop2_kernel(
    const float* __restrict__ h, const int* __restrict__ off_n,
    const int* __restrict__ csr_n2e, const float* __restrict__ m01,
    float* __restrict__ out) {
  const int n = blockIdx.x;
  const int g = threadIdx.x >> 5;
  const int l = threadIdx.x & 31;
  const int s   = off_n[n];
  const int end = (n == N_NODES - 1) ? NNZ : off_n[n + 1];
  const int cnt = end - s;

  f32x4 a0 = (f32x4){0.f,0.f,0.f,0.f}, a1 = a0;
  int j = g;
  for (; j + 12 < cnt; j += 16) {
    const int e0 = csr_n2e[s + j + 0];
    const int e1 = csr_n2e[s + j + 4];
    const int e2 = csr_n2e[s + j + 8];
    const int e3 = csr_n2e[s + j + 12];
    f32x4 v0 = *reinterpret_cast<const f32x4*>(&m01[(size_t)e0 * DIM + l * 4]);
    f32x4 v1 = *reinterpret_cast<const f32x4*>(&m01[(size_t)e1 * DIM + l * 4]);
    f32x4 v2 = *reinterpret_cast<const f32x4*>(&m01[(size_t)e2 * DIM + l * 4]);
    f32x4 v3 = *reinterpret_cast<const f32x4*>(&m01[(size_t)e3 * DIM + l * 4]);
    a0 += v0 + v2;
    a1 += v1 + v3;
  }
  for (; j < cnt; j += 4) {
    const int e = csr_n2e[s + j];
    a0 += *reinterpret_cast<const f32x4*>(&m01[(size_t)e * DIM + l * 4]);
  }

  __shared__ f32x4 red[128];
  red[threadIdx.x] = a0 + a1;
  __syncthreads();
  if (g == 0) {
    f32x4 r = red[l] + red[32 + l] + red[64 + l] + red[96 + l];
    f32x4 hv = *reinterpret_cast<const f32x4*>(&h[(size_t)n * DIM + l * 4]);
    const float inv = 1.0f / (float)(cnt > 0 ? cnt : 1);
    *reinterpret_cast<f32x4*>(&out[(size_t)n * DIM + l * 4]) = hv + r * inv;
  }
}

extern "C" void kernel_launch(void* const* d_in, const int* in_sizes, int n_in,
                              void* d_out, int out_size, void* d_ws, size_t ws_size,
                              hipStream_t stream) {
  const float* x    = (const float*)d_in[0];
  const float* W    = (const float*)d_in[1];
  const float* bias = (const float*)d_in[2];
  const int*   ni   = (const int*)d_in[3];
  const int*   ei   = (const int*)d_in[4];
  float* out = (float*)d_out;

  // ---- workspace carve ----
  char* ws = (char*)d_ws;
  size_t o = 0;
  auto carve = [&](size_t bytes) -> char* {
    char* p = ws + o;
    o = (o + bytes + 255) & ~(size_t)255;
    return p;
  };
  float*    h        = (float*)   carve((size_t)N_NODES * DIM * 4);   // 51.2 MB
  float*    m01      = (float*)   carve((size_t)N_EDGES * DIM * 4);   // 10.24 MB
  int*      csr_e2n  = (int*)     carve((size_t)NNZ * 4);             // 6.4 MB
  int*      csr_n2e  = (int*)     carve((size_t)NNZ * 4);             // 6.4 MB
  unsigned* rank     = (unsigned*)carve((size_t)NNZ * 4);             // 6.4 MB
  short*    Wb       = (short*)   carve((size_t)DIM * DIM * 2);       // 32 KB
  size_t zero_beg = o;
  int*      deg_n    = (int*)carve((size_t)N_NODES * PAD_N * 4);      // 3.2 MB padded
  int*      deg_e    = (int*)carve((size_t)N_EDGES * PAD_E * 4);      // 1.28 MB padded
  size_t zero_end = o;
  int*      off_n    = (int*)carve((size_t)N_NODES * 4);
  int*      off_e    = (int*)carve((size_t)N_EDGES * 4);
  int*      bsums    = (int*)carve(512 * 4);
  (void)ws_size; (void)in_sizes; (void)n_in; (void)out_size;

  // ---- zero degree arrays (workspace is poisoned; re-zero every call) ----
  hipMemsetAsync(ws + zero_beg, 0, zero_end - zero_beg, stream);

  // ---- W -> bf16 ----
  convw_kernel<<<(DIM * DIM + 255) / 256, 256, 0, stream>>>(W, Wb);

  // ---- GEMM h = x W^T + b ----
  gemm_kernel<<<(N_NODES / 16 + 3) / 4, 256, 0, stream>>>(x, Wb, bias, h);

  // ---- degree histogram + ranks (2 nnz per thread) ----
  hist_kernel<<<NNZ / 512, 256, 0, stream>>>(ni, ei, deg_n, deg_e, rank);

  // ---- exclusive scans: padded deg -> dense offsets ----
  {
    int nbl_e = (N_EDGES + 255) / 256;   // 79
    scan_block_kernel<<<nbl_e, 256, 0, stream>>>(deg_e, PAD_E, off_e, bsums, N_EDGES);
    scan_block_kernel<<<1, 512, 0, stream>>>(bsums, 1, bsums, nullptr, nbl_e);
    scan_add_kernel<<<nbl_e, 256, 0, stream>>>(off_e, bsums, N_EDGES);

    int nbl_n = (N_NODES + 255) / 256;   // 391
    scan_block_kernel<<<nbl_n, 256, 0, stream>>>(deg_n, PAD_N, off_n, bsums, N_NODES);
    scan_block_kernel<<<1, 512, 0, stream>>>(bsums, 1, bsums, nullptr, nbl_n);
    scan_add_kernel<<<nbl_n, 256, 0, stream>>>(off_n, bsums, N_NODES);
  }

  // ---- CSR scatter (pure stores) ----
  scatter_kernel<<<NNZ / 256, 256, 0, stream>>>(ni, ei, off_n, off_e, rank,
                                                csr_e2n, csr_n2e);

  // ---- hops ----
  hop1_kernel<<<N_EDGES, 128, 0, stream>>>(h, off_e, csr_e2n, m01);
  hop2_kernel<<<N_NODES, 128, 0, stream>>>(h, off_n, csr_n2e, m01, out);
}

// Round 4
// 369.404 us; speedup vs baseline: 1.6800x; 1.1735x over previous
//
#include <hip/hip_runtime.h>
#include <hip/hip_bf16.h>
#include <stddef.h>

// Problem constants (match reference setup_inputs)
#define N_NODES 100000
#define N_EDGES 20000
#define NNZ     1600000
#define DIM     128

// Edge LDS-histogram config
#define EH_BLOCKS  64
#define EH_THREADS 1024
#define EH_CHUNK   (NNZ / EH_BLOCKS)   // 25000 exactly

typedef short          bf16x8 __attribute__((ext_vector_type(8)));
typedef unsigned short u16x8  __attribute__((ext_vector_type(8)));
typedef float          f32x4  __attribute__((ext_vector_type(4)));
typedef float          f32x8  __attribute__((ext_vector_type(8)));

__device__ __forceinline__ unsigned short f2bf(float f) {
  union { float f; unsigned u; } c; c.f = f;
  unsigned r = c.u + 0x7FFFu + ((c.u >> 16) & 1u);   // round-to-nearest-even
  return (unsigned short)(r >> 16);
}

__device__ __forceinline__ f32x8 bf2f8(u16x8 v) {
  f32x8 r;
  #pragma unroll
  for (int i = 0; i < 8; ++i) {
    union { unsigned u; float f; } c; c.u = ((unsigned)v[i]) << 16;
    r[i] = c.f;
  }
  return r;
}

// ---------------- W fp32 -> bf16 ----------------
__global__ void convw_kernel(const float* __restrict__ W, unsigned short* __restrict__ Wb) {
  int i = blockIdx.x * 256 + threadIdx.x;
  if (i < DIM * DIM) Wb[i] = f2bf(W[i]);
}

// ---------------- GEMM: hb = bf16(x @ W^T + b) ----------------
// One wave: 16 rows x 128 cols. Fragment-row r of o-tile ot feeds W row (r*8+ot),
// so lane r owns 8 CONSECUTIVE output channels -> coalesced bf16x8 stores.
__global__ __launch_bounds__(256) void gemm_kernel(
    const float* __restrict__ x, const unsigned short* __restrict__ Wb,
    const float* __restrict__ bias, unsigned short* __restrict__ hb) {
  const int wid = threadIdx.x >> 6;
  const int l   = threadIdx.x & 63;
  const int n0  = (blockIdx.x * 4 + wid) * 16;
  if (n0 >= N_NODES) return;
  const int r  = l & 15;   // A-row within tile / B-fragment row
  const int kg = l >> 4;   // k-group (8 consecutive k per group)

  bf16x8 a[4];
  {
    const float* xr = x + (size_t)(n0 + r) * DIM + kg * 8;
    #pragma unroll
    for (int kc = 0; kc < 4; ++kc) {
      const float4* p = reinterpret_cast<const float4*>(xr + kc * 32);
      float4 f0 = p[0], f1 = p[1];
      bf16x8 av;
      av[0]=(short)f2bf(f0.x); av[1]=(short)f2bf(f0.y); av[2]=(short)f2bf(f0.z); av[3]=(short)f2bf(f0.w);
      av[4]=(short)f2bf(f1.x); av[5]=(short)f2bf(f1.y); av[6]=(short)f2bf(f1.z); av[7]=(short)f2bf(f1.w);
      a[kc] = av;
    }
  }

  f32x4 acc[8];
  #pragma unroll
  for (int ot = 0; ot < 8; ++ot) acc[ot] = (f32x4){0.f, 0.f, 0.f, 0.f};

  #pragma unroll
  for (int ot = 0; ot < 8; ++ot) {
    // permuted: o-tile ot, fragment row r <- W row (r*8 + ot)
    const unsigned short* wr = Wb + (size_t)(r * 8 + ot) * DIM + kg * 8;
    #pragma unroll
    for (int kc = 0; kc < 4; ++kc) {
      bf16x8 bfrag = *reinterpret_cast<const bf16x8*>(wr + kc * 32);
      acc[ot] = __builtin_amdgcn_mfma_f32_16x16x32_bf16(a[kc], bfrag, acc[ot], 0, 0, 0);
    }
  }

  // bias for this lane's 8 consecutive channels
  float bv[8];
  {
    const float4* bp = reinterpret_cast<const float4*>(bias + r * 8);
    float4 b0 = bp[0], b1 = bp[1];
    bv[0]=b0.x; bv[1]=b0.y; bv[2]=b0.z; bv[3]=b0.w;
    bv[4]=b1.x; bv[5]=b1.y; bv[6]=b1.z; bv[7]=b1.w;
  }

  // C/D: col(fragrow)=lane&15, row=(lane>>4)*4+reg  [m89]; col r of tile ot = channel r*8+ot
  #pragma unroll
  for (int j = 0; j < 4; ++j) {
    const int row = kg * 4 + j;
    u16x8 hv;
    #pragma unroll
    for (int ot = 0; ot < 8; ++ot) hv[ot] = f2bf(acc[ot][j] + bv[ot]);
    *reinterpret_cast<u16x8*>(&hb[(size_t)(n0 + row) * DIM + r * 8]) = hv;
  }
}

// ---------------- node histogram + rank (global atomics, 2 nnz/thread) ----------------
__global__ void nhist_kernel(const int* __restrict__ ni, int* __restrict__ dn,
                             unsigned short* __restrict__ rank_n) {
  const int i0 = blockIdx.x * 512 + threadIdx.x;
  const int i1 = i0 + 256;
  const int n0 = ni[i0], n1 = ni[i1];
  unsigned r0 = (unsigned)atomicAdd(&dn[n0], 1);
  unsigned r1 = (unsigned)atomicAdd(&dn[n1], 1);
  rank_n[i0] = (unsigned short)r0;
  rank_n[i1] = (unsigned short)r1;
}

// ---------------- edge histogram pass A: per-block LDS histograms ----------------
__global__ __launch_bounds__(EH_THREADS) void ehist_kernel(
    const int* __restrict__ ei, int* __restrict__ bh) {
  __shared__ int hist[N_EDGES];   // 80 KB
  for (int k = threadIdx.x; k < N_EDGES; k += EH_THREADS) hist[k] = 0;
  __syncthreads();
  const int base = blockIdx.x * EH_CHUNK;
  for (int i = base + threadIdx.x; i < base + EH_CHUNK; i += EH_THREADS)
    atomicAdd(&hist[ei[i]], 1);
  __syncthreads();
  for (int k = threadIdx.x; k < N_EDGES; k += EH_THREADS)
    bh[(size_t)k * EH_BLOCKS + blockIdx.x] = hist[k];
}

// ---------------- edge scan: per-key serial scan over blocks -> bases + totals ----------------
__global__ void escan_kernel(int* __restrict__ bh, int* __restrict__ deg_tmp) {
  int e = blockIdx.x * 256 + threadIdx.x;
  if (e >= N_EDGES) return;
  int* p = bh + (size_t)e * EH_BLOCKS;
  int base = 0;
  #pragma unroll 8
  for (int b = 0; b < EH_BLOCKS; ++b) { int t = p[b]; p[b] = base; base += t; }
  deg_tmp[e] = base;
}

// ---------------- edge rank pass B ----------------
__global__ __launch_bounds__(EH_THREADS) void erank_kernel(
    const int* __restrict__ ei, const int* __restrict__ bh,
    unsigned short* __restrict__ rank_e) {
  __shared__ int hist[N_EDGES];   // 80 KB
  for (int k = threadIdx.x; k < N_EDGES; k += EH_THREADS) hist[k] = 0;
  __syncthreads();
  const int base = blockIdx.x * EH_CHUNK;
  for (int i = base + threadIdx.x; i < base + EH_CHUNK; i += EH_THREADS) {
    int e = ei[i];
    int loc = atomicAdd(&hist[e], 1);
    rank_e[i] = (unsigned short)(bh[(size_t)e * EH_BLOCKS + blockIdx.x] + loc);
  }
}

// ---------------- hierarchical exclusive scan ----------------
__global__ void scan_block_kernel(const int* __restrict__ in, int* __restrict__ out,
                                  int* __restrict__ bsums, int n) {
  __shared__ int lds[512];
  const int tx = threadIdx.x;
  const int i  = blockIdx.x * blockDim.x + tx;
  int v = (i < n) ? in[i] : 0;
  int x = v;
  lds[tx] = x;
  __syncthreads();
  for (int off = 1; off < (int)blockDim.x; off <<= 1) {
    int t = (tx >= off) ? lds[tx - off] : 0;
    __syncthreads();
    x += t;
    lds[tx] = x;
    __syncthreads();
  }
  if (i < n) out[i] = x - v;                 // exclusive
  if (bsums && tx == (int)blockDim.x - 1) bsums[blockIdx.x] = x;  // total
}

__global__ void scan_add_kernel(int* __restrict__ out, const int* __restrict__ bsums, int n) {
  int i = blockIdx.x * blockDim.x + threadIdx.x;
  if (i < n) out[i] += bsums[blockIdx.x];
}

// ---------------- CSR scatter: pure stores ----------------
__global__ void scatter_kernel(const int* __restrict__ ni, const int* __restrict__ ei,
                               const int* __restrict__ off_n, const int* __restrict__ off_e,
                               const unsigned short* __restrict__ rank_n,
                               const unsigned short* __restrict__ rank_e,
                               int* __restrict__ csr_e2n, int* __restrict__ csr_n2e) {
  int i = blockIdx.x * 256 + threadIdx.x;
  if (i < NNZ) {
    int n = ni[i], e = ei[i];
    csr_e2n[off_e[e] + (int)rank_e[i]] = n;
    csr_n2e[off_n[n] + (int)rank_n[i]] = e;
  }
}

// ---------------- hop 1: m01b[e,:] = bf16( sum_{n in e} h[n,:] ) ----------------
// 256 threads = 16 groups x 16 lanes; lane loads bf16x8 (16B) -> group covers 256B row.
__global__ __launch_bounds__(256) void hop1_kernel(
    const unsigned short* __restrict__ hb, const int* __restrict__ off_e,
    const int* __restrict__ csr_e2n, unsigned short* __restrict__ m01b) {
  const int e = blockIdx.x;
  const int g = threadIdx.x >> 4;   // 0..15
  const int l = threadIdx.x & 15;
  const int s   = off_e[e];
  const int end = (e == N_EDGES - 1) ? NNZ : off_e[e + 1];

  f32x8 acc = (f32x8){0.f,0.f,0.f,0.f,0.f,0.f,0.f,0.f};
  int j = s + g;
  for (; j + 16 < end; j += 32) {
    const int n0 = csr_e2n[j];
    const int n1 = csr_e2n[j + 16];
    u16x8 v0 = *reinterpret_cast<const u16x8*>(&hb[(size_t)n0 * DIM + l * 8]);
    u16x8 v1 = *reinterpret_cast<const u16x8*>(&hb[(size_t)n1 * DIM + l * 8]);
    acc += bf2f8(v0) + bf2f8(v1);
  }
  for (; j < end; j += 16) {
    const int n = csr_e2n[j];
    acc += bf2f8(*reinterpret_cast<const u16x8*>(&hb[(size_t)n * DIM + l * 8]));
  }

  __shared__ f32x8 red[256];
  red[threadIdx.x] = acc;
  __syncthreads();
  if (threadIdx.x < 128) red[threadIdx.x] += red[threadIdx.x + 128];
  __syncthreads();
  if (threadIdx.x < 64)  red[threadIdx.x] += red[threadIdx.x + 64];
  __syncthreads();
  if (threadIdx.x < 32)  red[threadIdx.x] += red[threadIdx.x + 32];
  __syncthreads();
  if (threadIdx.x < 16) {
    f32x8 r = red[threadIdx.x] + red[threadIdx.x + 16];
    u16x8 o;
    #pragma unroll
    for (int i = 0; i < 8; ++i) o[i] = f2bf(r[i]);
    *reinterpret_cast<u16x8*>(&m01b[(size_t)e * DIM + threadIdx.x * 8]) = o;
  }
}

// ---------------- hop 2 + finalize: out[n,:] = h[n,:] + mean_{e ni n} m01[e,:] ----------------
// 128 threads = 8 groups x 16 lanes.
__global__ __launch_bounds__(128) void hop2_kernel(
    const unsigned short* __restrict__ hb, const int* __restrict__ off_n,
    const int* __restrict__ csr_n2e, const unsigned short* __restrict__ m01b,
    float* __restrict__ out) {
  const int n = blockIdx.x;
  const int g = threadIdx.x >> 4;   // 0..7
  const int l = threadIdx.x & 15;
  const int s   = off_n[n];
  const int end = (n == N_NODES - 1) ? NNZ : off_n[n + 1];
  const int cnt = end - s;

  f32x8 acc = (f32x8){0.f,0.f,0.f,0.f,0.f,0.f,0.f,0.f};
  for (int j = s + g; j < end; j += 8) {
    const int e = csr_n2e[j];
    acc += bf2f8(*reinterpret_cast<const u16x8*>(&m01b[(size_t)e * DIM + l * 8]));
  }

  __shared__ f32x8 red[128];
  red[threadIdx.x] = acc;
  __syncthreads();
  if (threadIdx.x < 64) red[threadIdx.x] += red[threadIdx.x + 64];
  __syncthreads();
  if (threadIdx.x < 32) red[threadIdx.x] += red[threadIdx.x + 32];
  __syncthreads();
  if (threadIdx.x < 16) {
    f32x8 r  = red[threadIdx.x] + red[threadIdx.x + 16];
    f32x8 hv = bf2f8(*reinterpret_cast<const u16x8*>(&hb[(size_t)n * DIM + threadIdx.x * 8]));
    const float inv = 1.0f / (float)(cnt > 0 ? cnt : 1);
    f32x8 o = hv + r * inv;
    float* op = &out[(size_t)n * DIM + threadIdx.x * 8];
    *reinterpret_cast<f32x4*>(op)     = (f32x4){o[0], o[1], o[2], o[3]};
    *reinterpret_cast<f32x4*>(op + 4) = (f32x4){o[4], o[5], o[6], o[7]};
  }
}

extern "C" void kernel_launch(void* const* d_in, const int* in_sizes, int n_in,
                              void* d_out, int out_size, void* d_ws, size_t ws_size,
                              hipStream_t stream) {
  const float* x    = (const float*)d_in[0];
  const float* W    = (const float*)d_in[1];
  const float* bias = (const float*)d_in[2];
  const int*   ni   = (const int*)d_in[3];
  const int*   ei   = (const int*)d_in[4];
  float* out = (float*)d_out;

  // ---- workspace carve ----
  char* ws = (char*)d_ws;
  size_t o = 0;
  auto carve = [&](size_t bytes) -> char* {
    char* p = ws + o;
    o = (o + bytes + 255) & ~(size_t)255;
    return p;
  };
  unsigned short* hb      = (unsigned short*)carve((size_t)N_NODES * DIM * 2);  // 25.6 MB
  unsigned short* m01b    = (unsigned short*)carve((size_t)N_EDGES * DIM * 2);  // 5.12 MB
  int*            csr_e2n = (int*)           carve((size_t)NNZ * 4);            // 6.4 MB
  int*            csr_n2e = (int*)           carve((size_t)NNZ * 4);            // 6.4 MB
  unsigned short* rank_n  = (unsigned short*)carve((size_t)NNZ * 2);            // 3.2 MB
  unsigned short* rank_e  = (unsigned short*)carve((size_t)NNZ * 2);            // 3.2 MB
  unsigned short* Wb      = (unsigned short*)carve((size_t)DIM * DIM * 2);      // 32 KB
  int*            bh      = (int*)           carve((size_t)N_EDGES * EH_BLOCKS * 4); // 5.12 MB
  size_t zero_beg = o;
  int*            deg_n   = (int*)carve((size_t)N_NODES * 4);                   // 400 KB
  size_t zero_end = o;
  int*            deg_tmp = (int*)carve((size_t)N_EDGES * 4);
  int*            off_n   = (int*)carve((size_t)N_NODES * 4);
  int*            off_e   = (int*)carve((size_t)N_EDGES * 4);
  int*            bsums   = (int*)carve(512 * 4);
  (void)ws_size; (void)in_sizes; (void)n_in; (void)out_size;

  // ---- zero node-degree counters (workspace is poisoned; re-zero every call) ----
  hipMemsetAsync(ws + zero_beg, 0, zero_end - zero_beg, stream);

  // ---- W -> bf16, GEMM ----
  convw_kernel<<<(DIM * DIM + 255) / 256, 256, 0, stream>>>(W, Wb);
  gemm_kernel<<<(N_NODES / 16 + 3) / 4, 256, 0, stream>>>(x, Wb, bias, hb);

  // ---- node ranks (global atomics) ----
  nhist_kernel<<<NNZ / 512, 256, 0, stream>>>(ni, deg_n, rank_n);

  // ---- edge ranks (LDS two-pass) ----
  ehist_kernel<<<EH_BLOCKS, EH_THREADS, 0, stream>>>(ei, bh);
  escan_kernel<<<(N_EDGES + 255) / 256, 256, 0, stream>>>(bh, deg_tmp);
  erank_kernel<<<EH_BLOCKS, EH_THREADS, 0, stream>>>(ei, bh, rank_e);

  // ---- exclusive scans: deg -> offsets ----
  {
    int nbl_e = (N_EDGES + 255) / 256;   // 79
    scan_block_kernel<<<nbl_e, 256, 0, stream>>>(deg_tmp, off_e, bsums, N_EDGES);
    scan_block_kernel<<<1, 512, 0, stream>>>(bsums, bsums, nullptr, nbl_e);
    scan_add_kernel<<<nbl_e, 256, 0, stream>>>(off_e, bsums, N_EDGES);

    int nbl_n = (N_NODES + 255) / 256;   // 391
    scan_block_kernel<<<nbl_n, 256, 0, stream>>>(deg_n, off_n, bsums, N_NODES);
    scan_block_kernel<<<1, 512, 0, stream>>>(bsums, bsums, nullptr, nbl_n);
    scan_add_kernel<<<nbl_n, 256, 0, stream>>>(off_n, bsums, N_NODES);
  }

  // ---- CSR scatter (pure stores) ----
  scatter_kernel<<<NNZ / 256, 256, 0, stream>>>(ni, ei, off_n, off_e,
                                                rank_n, rank_e, csr_e2n, csr_n2e);

  // ---- hops ----
  hop1_kernel<<<N_EDGES, 256, 0, stream>>>(hb, off_e, csr_e2n, m01b);
  hop2_kernel<<<N_NODES, 128, 0, stream>>>(hb, off_n, csr_n2e, m01b, out);
}

// Round 5
// 342.766 us; speedup vs baseline: 1.8106x; 1.0777x over previous
//
#include <hip/hip_runtime.h>
#include <hip/hip_bf16.h>
#include <stddef.h>

// Problem constants (match reference setup_inputs)
#define N_NODES 100000
#define N_EDGES 20000
#define NNZ     1600000
#define DIM     128

// Edge LDS-histogram config
#define EH_BLOCKS  64
#define EH_THREADS 1024
#define EH_CHUNK   (NNZ / EH_BLOCKS)   // 25000 exactly

typedef short          bf16x8 __attribute__((ext_vector_type(8)));
typedef unsigned short u16x8  __attribute__((ext_vector_type(8)));
typedef float          f32x4  __attribute__((ext_vector_type(4)));
typedef float          f32x8  __attribute__((ext_vector_type(8)));

__device__ __forceinline__ unsigned short f2bf(float f) {
  union { float f; unsigned u; } c; c.f = f;
  unsigned r = c.u + 0x7FFFu + ((c.u >> 16) & 1u);   // round-to-nearest-even
  return (unsigned short)(r >> 16);
}

__device__ __forceinline__ f32x8 bf2f8(u16x8 v) {
  f32x8 r;
  #pragma unroll
  for (int i = 0; i < 8; ++i) {
    union { unsigned u; float f; } c; c.u = ((unsigned)v[i]) << 16;
    r[i] = c.f;
  }
  return r;
}

// ---------------- W fp32 -> bf16 ----------------
__global__ void convw_kernel(const float* __restrict__ W, unsigned short* __restrict__ Wb) {
  int i = blockIdx.x * 256 + threadIdx.x;
  if (i < DIM * DIM) Wb[i] = f2bf(W[i]);
}

// ---------------- GEMM: hb = bf16(x @ W^T + b) ----------------
// One wave: 16 rows x 128 cols. Fragment-row r of o-tile ot feeds W row (r*8+ot),
// so lane r owns 8 CONSECUTIVE output channels -> coalesced bf16x8 stores.
__global__ __launch_bounds__(256) void gemm_kernel(
    const float* __restrict__ x, const unsigned short* __restrict__ Wb,
    const float* __restrict__ bias, unsigned short* __restrict__ hb) {
  const int wid = threadIdx.x >> 6;
  const int l   = threadIdx.x & 63;
  const int n0  = (blockIdx.x * 4 + wid) * 16;
  if (n0 >= N_NODES) return;
  const int r  = l & 15;   // A-row within tile / B-fragment row
  const int kg = l >> 4;   // k-group (8 consecutive k per group)

  bf16x8 a[4];
  {
    const float* xr = x + (size_t)(n0 + r) * DIM + kg * 8;
    #pragma unroll
    for (int kc = 0; kc < 4; ++kc) {
      const float4* p = reinterpret_cast<const float4*>(xr + kc * 32);
      float4 f0 = p[0], f1 = p[1];
      bf16x8 av;
      av[0]=(short)f2bf(f0.x); av[1]=(short)f2bf(f0.y); av[2]=(short)f2bf(f0.z); av[3]=(short)f2bf(f0.w);
      av[4]=(short)f2bf(f1.x); av[5]=(short)f2bf(f1.y); av[6]=(short)f2bf(f1.z); av[7]=(short)f2bf(f1.w);
      a[kc] = av;
    }
  }

  f32x4 acc[8];
  #pragma unroll
  for (int ot = 0; ot < 8; ++ot) acc[ot] = (f32x4){0.f, 0.f, 0.f, 0.f};

  #pragma unroll
  for (int ot = 0; ot < 8; ++ot) {
    // permuted: o-tile ot, fragment row r <- W row (r*8 + ot)
    const unsigned short* wr = Wb + (size_t)(r * 8 + ot) * DIM + kg * 8;
    #pragma unroll
    for (int kc = 0; kc < 4; ++kc) {
      bf16x8 bfrag = *reinterpret_cast<const bf16x8*>(wr + kc * 32);
      acc[ot] = __builtin_amdgcn_mfma_f32_16x16x32_bf16(a[kc], bfrag, acc[ot], 0, 0, 0);
    }
  }

  // bias for this lane's 8 consecutive channels
  float bv[8];
  {
    const float4* bp = reinterpret_cast<const float4*>(bias + r * 8);
    float4 b0 = bp[0], b1 = bp[1];
    bv[0]=b0.x; bv[1]=b0.y; bv[2]=b0.z; bv[3]=b0.w;
    bv[4]=b1.x; bv[5]=b1.y; bv[6]=b1.z; bv[7]=b1.w;
  }

  // C/D: col(fragrow)=lane&15, row=(lane>>4)*4+reg  [m89]; col r of tile ot = channel r*8+ot
  #pragma unroll
  for (int j = 0; j < 4; ++j) {
    const int row = kg * 4 + j;
    u16x8 hv;
    #pragma unroll
    for (int ot = 0; ot < 8; ++ot) hv[ot] = f2bf(acc[ot][j] + bv[ot]);
    *reinterpret_cast<u16x8*>(&hb[(size_t)(n0 + row) * DIM + r * 8]) = hv;
  }
}

// ---------------- node histogram + rank (global atomics, 2 nnz/thread) ----------------
__global__ void nhist_kernel(const int* __restrict__ ni, int* __restrict__ dn,
                             unsigned short* __restrict__ rank_n) {
  const int i0 = blockIdx.x * 512 + threadIdx.x;
  const int i1 = i0 + 256;
  const int n0 = ni[i0], n1 = ni[i1];
  unsigned r0 = (unsigned)atomicAdd(&dn[n0], 1);
  unsigned r1 = (unsigned)atomicAdd(&dn[n1], 1);
  rank_n[i0] = (unsigned short)r0;
  rank_n[i1] = (unsigned short)r1;
}

// ---------------- edge histogram pass A: per-block LDS histograms ----------------
__global__ __launch_bounds__(EH_THREADS) void ehist_kernel(
    const int* __restrict__ ei, int* __restrict__ bh) {
  __shared__ int hist[N_EDGES];   // 80 KB
  for (int k = threadIdx.x; k < N_EDGES; k += EH_THREADS) hist[k] = 0;
  __syncthreads();
  const int base = blockIdx.x * EH_CHUNK;
  for (int i = base + threadIdx.x; i < base + EH_CHUNK; i += EH_THREADS)
    atomicAdd(&hist[ei[i]], 1);
  __syncthreads();
  for (int k = threadIdx.x; k < N_EDGES; k += EH_THREADS)
    bh[(size_t)k * EH_BLOCKS + blockIdx.x] = hist[k];
}

// ---------------- edge scan: per-key serial scan over blocks -> bases + totals ----------------
__global__ void escan_kernel(int* __restrict__ bh, int* __restrict__ deg_tmp) {
  int e = blockIdx.x * 256 + threadIdx.x;
  if (e >= N_EDGES) return;
  int* p = bh + (size_t)e * EH_BLOCKS;
  int base = 0;
  #pragma unroll 8
  for (int b = 0; b < EH_BLOCKS; ++b) { int t = p[b]; p[b] = base; base += t; }
  deg_tmp[e] = base;
}

// ---------------- edge rank pass B ----------------
__global__ __launch_bounds__(EH_THREADS) void erank_kernel(
    const int* __restrict__ ei, const int* __restrict__ bh,
    unsigned short* __restrict__ rank_e) {
  __shared__ int hist[N_EDGES];   // 80 KB
  for (int k = threadIdx.x; k < N_EDGES; k += EH_THREADS) hist[k] = 0;
  __syncthreads();
  const int base = blockIdx.x * EH_CHUNK;
  for (int i = base + threadIdx.x; i < base + EH_CHUNK; i += EH_THREADS) {
    int e = ei[i];
    int loc = atomicAdd(&hist[e], 1);
    rank_e[i] = (unsigned short)(bh[(size_t)e * EH_BLOCKS + blockIdx.x] + loc);
  }
}

// ---------------- hierarchical exclusive scan ----------------
__global__ void scan_block_kernel(const int* __restrict__ in, int* __restrict__ out,
                                  int* __restrict__ bsums, int n) {
  __shared__ int lds[512];
  const int tx = threadIdx.x;
  const int i  = blockIdx.x * blockDim.x + tx;
  int v = (i < n) ? in[i] : 0;
  int x = v;
  lds[tx] = x;
  __syncthreads();
  for (int off = 1; off < (int)blockDim.x; off <<= 1) {
    int t = (tx >= off) ? lds[tx - off] : 0;
    __syncthreads();
    x += t;
    lds[tx] = x;
    __syncthreads();
  }
  if (i < n) out[i] = x - v;                 // exclusive
  if (bsums && tx == (int)blockDim.x - 1) bsums[blockIdx.x] = x;  // total
}

__global__ void scan_add_kernel(int* __restrict__ out, const int* __restrict__ bsums, int n) {
  int i = blockIdx.x * blockDim.x + threadIdx.x;
  if (i < n) out[i] += bsums[blockIdx.x];
}

// ---------------- CSR scatter: pure stores ----------------
__global__ void scatter_kernel(const int* __restrict__ ni, const int* __restrict__ ei,
                               const int* __restrict__ off_n, const int* __restrict__ off_e,
                               const unsigned short* __restrict__ rank_n,
                               const unsigned short* __restrict__ rank_e,
                               int* __restrict__ csr_e2n, int* __restrict__ csr_n2e) {
  int i = blockIdx.x * 256 + threadIdx.x;
  if (i < NNZ) {
    int n = ni[i], e = ei[i];
    csr_e2n[off_e[e] + (int)rank_e[i]] = n;
    csr_n2e[off_n[n] + (int)rank_n[i]] = e;
  }
}

// ---------------- hop 1: m01b[e,:] = bf16( sum_{n in e} h[n,:] ) ----------------
// One 16-lane group owns one edge segment serially (no LDS, no syncs).
// 256 threads = 16 edges per block. 4-deep unroll for MLP.
__global__ __launch_bounds__(256) void hop1_kernel(
    const unsigned short* __restrict__ hb, const int* __restrict__ off_e,
    const int* __restrict__ csr_e2n, unsigned short* __restrict__ m01b) {
  const int e = blockIdx.x * 16 + (threadIdx.x >> 4);
  const int l = threadIdx.x & 15;
  if (e >= N_EDGES) return;
  const int s   = off_e[e];
  const int end = (e == N_EDGES - 1) ? NNZ : off_e[e + 1];

  f32x8 a0 = (f32x8){0.f,0.f,0.f,0.f,0.f,0.f,0.f,0.f};
  f32x8 a1 = a0, a2 = a0, a3 = a0;
  int j = s;
  for (; j + 3 < end; j += 4) {
    const int n0 = csr_e2n[j + 0];
    const int n1 = csr_e2n[j + 1];
    const int n2 = csr_e2n[j + 2];
    const int n3 = csr_e2n[j + 3];
    u16x8 v0 = *reinterpret_cast<const u16x8*>(&hb[(size_t)n0 * DIM + l * 8]);
    u16x8 v1 = *reinterpret_cast<const u16x8*>(&hb[(size_t)n1 * DIM + l * 8]);
    u16x8 v2 = *reinterpret_cast<const u16x8*>(&hb[(size_t)n2 * DIM + l * 8]);
    u16x8 v3 = *reinterpret_cast<const u16x8*>(&hb[(size_t)n3 * DIM + l * 8]);
    a0 += bf2f8(v0); a1 += bf2f8(v1); a2 += bf2f8(v2); a3 += bf2f8(v3);
  }
  for (; j < end; ++j) {
    const int n = csr_e2n[j];
    a0 += bf2f8(*reinterpret_cast<const u16x8*>(&hb[(size_t)n * DIM + l * 8]));
  }
  f32x8 r = (a0 + a1) + (a2 + a3);
  u16x8 o;
  #pragma unroll
  for (int i = 0; i < 8; ++i) o[i] = f2bf(r[i]);
  *reinterpret_cast<u16x8*>(&m01b[(size_t)e * DIM + l * 8]) = o;
}

// ---------------- hop 2 + finalize: out[n,:] = h[n,:] + mean_{e ni n} m01[e,:] ----------------
// One 16-lane group owns one node segment serially. 256 threads = 16 nodes/block.
__global__ __launch_bounds__(256) void hop2_kernel(
    const unsigned short* __restrict__ hb, const int* __restrict__ off_n,
    const int* __restrict__ csr_n2e, const unsigned short* __restrict__ m01b,
    float* __restrict__ out) {
  const int n = blockIdx.x * 16 + (threadIdx.x >> 4);
  const int l = threadIdx.x & 15;
  if (n >= N_NODES) return;
  const int s   = off_n[n];
  const int end = (n == N_NODES - 1) ? NNZ : off_n[n + 1];
  const int cnt = end - s;

  f32x8 a0 = (f32x8){0.f,0.f,0.f,0.f,0.f,0.f,0.f,0.f};
  f32x8 a1 = a0;
  int j = s;
  for (; j + 1 < end; j += 2) {
    const int e0 = csr_n2e[j + 0];
    const int e1 = csr_n2e[j + 1];
    u16x8 v0 = *reinterpret_cast<const u16x8*>(&m01b[(size_t)e0 * DIM + l * 8]);
    u16x8 v1 = *reinterpret_cast<const u16x8*>(&m01b[(size_t)e1 * DIM + l * 8]);
    a0 += bf2f8(v0); a1 += bf2f8(v1);
  }
  if (j < end) {
    const int e = csr_n2e[j];
    a0 += bf2f8(*reinterpret_cast<const u16x8*>(&m01b[(size_t)e * DIM + l * 8]));
  }
  f32x8 r  = a0 + a1;
  f32x8 hv = bf2f8(*reinterpret_cast<const u16x8*>(&hb[(size_t)n * DIM + l * 8]));
  const float inv = 1.0f / (float)(cnt > 0 ? cnt : 1);
  f32x8 o = hv + r * inv;
  float* op = &out[(size_t)n * DIM + l * 8];
  *reinterpret_cast<f32x4*>(op)     = (f32x4){o[0], o[1], o[2], o[3]};
  *reinterpret_cast<f32x4*>(op + 4) = (f32x4){o[4], o[5], o[6], o[7]};
}

extern "C" void kernel_launch(void* const* d_in, const int* in_sizes, int n_in,
                              void* d_out, int out_size, void* d_ws, size_t ws_size,
                              hipStream_t stream) {
  const float* x    = (const float*)d_in[0];
  const float* W    = (const float*)d_in[1];
  const float* bias = (const float*)d_in[2];
  const int*   ni   = (const int*)d_in[3];
  const int*   ei   = (const int*)d_in[4];
  float* out = (float*)d_out;

  // ---- workspace carve ----
  char* ws = (char*)d_ws;
  size_t o = 0;
  auto carve = [&](size_t bytes) -> char* {
    char* p = ws + o;
    o = (o + bytes + 255) & ~(size_t)255;
    return p;
  };
  unsigned short* hb      = (unsigned short*)carve((size_t)N_NODES * DIM * 2);  // 25.6 MB
  unsigned short* m01b    = (unsigned short*)carve((size_t)N_EDGES * DIM * 2);  // 5.12 MB
  int*            csr_e2n = (int*)           carve((size_t)NNZ * 4);            // 6.4 MB
  int*            csr_n2e = (int*)           carve((size_t)NNZ * 4);            // 6.4 MB
  unsigned short* rank_n  = (unsigned short*)carve((size_t)NNZ * 2);            // 3.2 MB
  unsigned short* rank_e  = (unsigned short*)carve((size_t)NNZ * 2);            // 3.2 MB
  unsigned short* Wb      = (unsigned short*)carve((size_t)DIM * DIM * 2);      // 32 KB
  int*            bh      = (int*)           carve((size_t)N_EDGES * EH_BLOCKS * 4); // 5.12 MB
  size_t zero_beg = o;
  int*            deg_n   = (int*)carve((size_t)N_NODES * 4);                   // 400 KB
  size_t zero_end = o;
  int*            deg_tmp = (int*)carve((size_t)N_EDGES * 4);
  int*            off_n   = (int*)carve((size_t)N_NODES * 4);
  int*            off_e   = (int*)carve((size_t)N_EDGES * 4);
  int*            bsums   = (int*)carve(512 * 4);
  (void)ws_size; (void)in_sizes; (void)n_in; (void)out_size;

  // ---- zero node-degree counters (workspace is poisoned; re-zero every call) ----
  hipMemsetAsync(ws + zero_beg, 0, zero_end - zero_beg, stream);

  // ---- W -> bf16, GEMM ----
  convw_kernel<<<(DIM * DIM + 255) / 256, 256, 0, stream>>>(W, Wb);
  gemm_kernel<<<(N_NODES / 16 + 3) / 4, 256, 0, stream>>>(x, Wb, bias, hb);

  // ---- node ranks (global atomics) ----
  nhist_kernel<<<NNZ / 512, 256, 0, stream>>>(ni, deg_n, rank_n);

  // ---- edge ranks (LDS two-pass) ----
  ehist_kernel<<<EH_BLOCKS, EH_THREADS, 0, stream>>>(ei, bh);
  escan_kernel<<<(N_EDGES + 255) / 256, 256, 0, stream>>>(bh, deg_tmp);
  erank_kernel<<<EH_BLOCKS, EH_THREADS, 0, stream>>>(ei, bh, rank_e);

  // ---- exclusive scans: deg -> offsets ----
  {
    int nbl_e = (N_EDGES + 255) / 256;   // 79
    scan_block_kernel<<<nbl_e, 256, 0, stream>>>(deg_tmp, off_e, bsums, N_EDGES);
    scan_block_kernel<<<1, 512, 0, stream>>>(bsums, bsums, nullptr, nbl_e);
    scan_add_kernel<<<nbl_e, 256, 0, stream>>>(off_e, bsums, N_EDGES);

    int nbl_n = (N_NODES + 255) / 256;   // 391
    scan_block_kernel<<<nbl_n, 256, 0, stream>>>(deg_n, off_n, bsums, N_NODES);
    scan_block_kernel<<<1, 512, 0, stream>>>(bsums, bsums, nullptr, nbl_n);
    scan_add_kernel<<<nbl_n, 256, 0, stream>>>(off_n, bsums, N_NODES);
  }

  // ---- CSR scatter (pure stores) ----
  scatter_kernel<<<NNZ / 256, 256, 0, stream>>>(ni, ei, off_n, off_e,
                                                rank_n, rank_e, csr_e2n, csr_n2e);

  // ---- hops ----
  hop1_kernel<<<(N_EDGES + 15) / 16, 256, 0, stream>>>(hb, off_e, csr_e2n, m01b);
  hop2_kernel<<<(N_NODES + 15) / 16, 256, 0, stream>>>(hb, off_n, csr_n2e, m01b, out);
}